// Round 7
// baseline (1272.314 us; speedup 1.0000x reference)
//
#include <hip/hip_runtime.h>
#include <math.h>

#define NB 1024
#define NHEX 19
#define NVERT 54
#define NEDGE 72
#define NNODE 145   /* hex[0,19) vert[19,73) edge[73,145) */
#define HID 128
#define NLAYERS 3
#define MAXE 144
#define OUTD 256
#define FPLY 14
#define POOLD 398

typedef unsigned short ushort_t;
typedef short bf16x8 __attribute__((ext_vector_type(8)));
typedef float f32x4 __attribute__((ext_vector_type(4)));
typedef float f32x2 __attribute__((ext_vector_type(2)));

static __device__ __forceinline__ float bf2f(ushort_t u) {
    return __uint_as_float(((unsigned int)u) << 16);
}
static __device__ __forceinline__ ushort_t f2bf(float f) {
    unsigned int u = __float_as_uint(f);
    return (ushort_t)((u + 0x7fffu + ((u >> 16) & 1u)) >> 16);
}
/* packed f32->bf16x2 via HW cvt (RNE) */
static __device__ __forceinline__ unsigned pk2(float lo, float hi) {
    unsigned r;
    asm("v_cvt_pk_bf16_f32 %0, %1, %2" : "=v"(r) : "v"(lo), "v"(hi));
    return r;
}
static __device__ __forceinline__ float blo(unsigned u) { return __uint_as_float(u << 16); }
static __device__ __forceinline__ float bhi(unsigned u) { return __uint_as_float(u & 0xffff0000u); }
static __device__ __forceinline__ f32x4 MF(uint4 a, uint4 b, f32x4 c) {
    return __builtin_amdgcn_mfma_f32_16x16x32_bf16(
        __builtin_bit_cast(bf16x8, a), __builtin_bit_cast(bf16x8, b), c, 0, 0, 0);
}

/* ================= topology (numpy RandomState(0) replica) + dedup CSR ============ */
__device__ __forceinline__ void topo_body(int* __restrict__ cst_g, unsigned* __restrict__ pck_g) {
    __shared__ unsigned mt[624];
    __shared__ int t6[624];
    __shared__ int sc[624];
    __shared__ int hv[114], v0a[72], v1a[72];
    __shared__ int cnt[80];
    __shared__ int dloc[73 * 24];
    __shared__ int J186;
    const int tid = threadIdx.x;

    if (tid == 0) {
        unsigned s = 0u;
        for (int i = 0; i < 624; ++i) { mt[i] = s; s = 1812433253u * (s ^ (s >> 30)) + (unsigned)i + 1u; }
    }
    __syncthreads();
    {
        unsigned a = 0, bb = 0, c = 0;
        if (tid < 227) { a = mt[tid]; bb = mt[tid + 1]; c = mt[tid + 397]; }
        __syncthreads();
        if (tid < 227) {
            unsigned y = (a & 0x80000000u) | (bb & 0x7fffffffu);
            mt[tid] = c ^ (y >> 1) ^ ((bb & 1u) ? 0x9908b0dfu : 0u);
        }
        __syncthreads();
    }
    {
        int i = 227 + tid;
        unsigned a = 0, bb = 0, c = 0;
        if (tid < 227) { a = mt[i]; bb = mt[i + 1]; c = mt[i - 227]; }
        __syncthreads();
        if (tid < 227) {
            unsigned y = (a & 0x80000000u) | (bb & 0x7fffffffu);
            mt[i] = c ^ (y >> 1) ^ ((bb & 1u) ? 0x9908b0dfu : 0u);
        }
        __syncthreads();
    }
    {
        int i = 454 + tid;
        unsigned a = 0, bb = 0, c = 0;
        if (tid < 170) { a = mt[i]; bb = mt[(i + 1) % 624]; c = mt[i - 227]; }
        __syncthreads();
        if (tid < 170) {
            unsigned y = (a & 0x80000000u) | (bb & 0x7fffffffu);
            mt[i] = c ^ (y >> 1) ^ ((bb & 1u) ? 0x9908b0dfu : 0u);
        }
        __syncthreads();
    }
    for (int i = tid; i < 624; i += 256) {
        unsigned y = mt[i];
        y ^= y >> 11; y ^= (y << 7) & 0x9d2c5680u; y ^= (y << 15) & 0xefc60000u; y ^= y >> 18;
        t6[i] = (int)(y & 63u);
    }
    __syncthreads();
#define SCAN624()                                                          \
    for (int off = 1; off < 624; off <<= 1) {                              \
        int v0_ = 0, v1_ = 0, v2_ = 0;                                     \
        int i0 = tid, i1 = tid + 256, i2 = tid + 512;                      \
        if (i0 >= off) v0_ = sc[i0 - off];                                 \
        if (i1 >= off) v1_ = sc[i1 - off];                                 \
        if (i2 < 624 && i2 >= off) v2_ = sc[i2 - off];                     \
        __syncthreads();                                                   \
        sc[i0] += v0_; sc[i1] += v1_;                                      \
        if (i2 < 624) sc[i2] += v2_;                                       \
        __syncthreads();                                                   \
    }
    for (int i = tid; i < 624; i += 256) sc[i] = (t6[i] <= 53) ? 1 : 0;
    __syncthreads();
    SCAN624();
    for (int i = tid; i < 624; i += 256) {
        if (t6[i] <= 53) {
            int k = sc[i];
            if (k <= 114) hv[k - 1] = t6[i];
            else if (k <= 186) v0a[k - 115] = t6[i];
            if (k == 186) J186 = i;
        }
    }
    __syncthreads();
    int Jcap = J186;
    for (int i = tid; i < 624; i += 256) sc[i] = (i > Jcap && t6[i] <= 52) ? 1 : 0;
    __syncthreads();
    SCAN624();
    for (int i = tid; i < 624; i += 256) {
        if (i > Jcap && t6[i] <= 52) {
            int k = sc[i];
            if (k <= 72) v1a[k - 1] = (v0a[k - 1] + 1 + t6[i]) % 54;
        }
    }
    __syncthreads();
#undef SCAN624
    /* dedup CSR per relation: pck = s | d<<8 | mult<<16 */
    const int En[5] = {114, 114, 144, 144, 144};
    const int Ndn[5] = {54, 19, 72, 54, 54};
    for (int r = 0; r < 5; ++r) {
        int E = En[r], Nd = Ndn[r];
        int myc = 0;
        if (tid < Nd) {
            int* ss = dloc + tid * 24;
            for (int k = 0; k < E; ++k) {
                int s, d;
                if (r == 0)      { s = k / 6; d = hv[k]; }
                else if (r == 1) { s = hv[k]; d = k / 6; }
                else if (r == 2) { s = (k & 1) ? v1a[k >> 1] : v0a[k >> 1]; d = k >> 1; }
                else if (r == 3) { s = k >> 1; d = (k & 1) ? v1a[k >> 1] : v0a[k >> 1]; }
                else             { s = (k < 72) ? v0a[k] : v1a[k - 72]; d = (k < 72) ? v1a[k] : v0a[k - 72]; }
                if (d != tid) continue;
                int f = -1;
                for (int i2 = 0; i2 < myc; ++i2) if ((ss[i2] & 255) == s) { f = i2; break; }
                if (f >= 0) ss[f] += 1 << 16;
                else { if (myc < 24) { ss[myc++] = s | (1 << 16); } }
            }
            cnt[tid] = myc;
        }
        __syncthreads();
        for (int off = 1; off < 128; off <<= 1) {
            int v = 0;
            if (tid < Nd && tid >= off) v = cnt[tid - off];
            __syncthreads();
            if (tid < Nd && tid >= off) cnt[tid] += v;
            __syncthreads();
        }
        if (tid < Nd) {
            int st = cnt[tid] - myc;
            cst_g[r * 73 + tid] = st;
            if (tid == Nd - 1) cst_g[r * 73 + Nd] = cnt[tid];
            int* ss = dloc + tid * 24;
            for (int i2 = 0; i2 < myc; ++i2)
                pck_g[r * 144 + st + i2] =
                    (unsigned)((ss[i2] & 255) | (tid << 8) | ((ss[i2] >> 16) << 16));
        }
        __syncthreads();
    }
}

/* -------- attention vectors, packed 16-vec tile: vec h=was_hi, 4+h=wad_hi, 8+h=was_lo, 12+h=wad_lo -- */
__device__ __forceinline__ void wvec_body(int lr, const float* __restrict__ gat_W,
                                          const float* __restrict__ gat_asrc,
                                          const float* __restrict__ gat_adst,
                                          ushort_t* __restrict__ wvb) {
    __shared__ float as_s[512], ad_s[512];
    int tid = threadIdx.x;
    for (int i = tid; i < 512; i += 256) {
        as_s[i] = gat_asrc[(size_t)lr * 512 + i];
        ad_s[i] = gat_adst[(size_t)lr * 512 + i];
    }
    __syncthreads();
    ushort_t* wb = wvb + (size_t)lr * 2048;
    const float* W = gat_W + (size_t)lr * 128 * 512;
    int t127 = tid & 127, rhalf = tid >> 7;
    int h = t127 >> 5, c4 = t127 & 31;
    for (int k0 = 0; k0 < 128; k0 += 2) {
        int k = k0 + rhalf;
        float4 wv4 = *(const float4*)(W + (size_t)k * 512 + h * 128 + c4 * 4);
        const float* a = as_s + h * 128 + c4 * 4;
        const float* dd = ad_s + h * 128 + c4 * 4;
        float pa = wv4.x * a[0] + wv4.y * a[1] + wv4.z * a[2] + wv4.w * a[3];
        float pd = wv4.x * dd[0] + wv4.y * dd[1] + wv4.z * dd[2] + wv4.w * dd[3];
        for (int m = 1; m < 32; m <<= 1) { pa += __shfl_xor(pa, m, 64); pd += __shfl_xor(pd, m, 64); }
        if (c4 == 0) {
            ushort_t pah = f2bf(pa), pdh = f2bf(pd);
            ushort_t pal = f2bf(pa - bf2f(pah)), pdl = f2bf(pd - bf2f(pdh));
            wb[h * 128 + k] = pah;        wb[(4 + h) * 128 + k] = pdh;
            wb[(8 + h) * 128 + k] = pal;  wb[(12 + h) * 128 + k] = pdl;
        }
    }
}

/* -------- Wp[lr][h][n][k] = bf16(gat_W[lr][k][h*128+n]) -------- */
__device__ __forceinline__ void wp_body(int lrh, const float* __restrict__ gat_W, ushort_t* __restrict__ Wp) {
    __shared__ ushort_t tr[128 * 130];
    int lr = lrh >> 2, h = lrh & 3;
    const float* Wsrc = gat_W + (size_t)lr * 128 * 512 + h * 128;
    for (int i = threadIdx.x; i < 128 * 32; i += 256) {
        int k = i >> 5, q = i & 31;
        float4 v = *(const float4*)(Wsrc + (size_t)k * 512 + q * 4);
        int n = q * 4;
        tr[(n + 0) * 130 + k] = f2bf(v.x);
        tr[(n + 1) * 130 + k] = f2bf(v.y);
        tr[(n + 2) * 130 + k] = f2bf(v.z);
        tr[(n + 3) * 130 + k] = f2bf(v.w);
    }
    __syncthreads();
    ushort_t* dst = Wp + (size_t)lrh * 128 * 128;
    for (int i = threadIdx.x; i < 128 * 16; i += 256) {
        int n = i >> 4, q = i & 15;
        const ushort_t* s = tr + n * 130 + q * 8;
        uint4 o;
        o.x = (unsigned)s[0] | ((unsigned)s[1] << 16);
        o.y = (unsigned)s[2] | ((unsigned)s[3] << 16);
        o.z = (unsigned)s[4] | ((unsigned)s[5] << 16);
        o.w = (unsigned)s[6] | ((unsigned)s[7] << 16);
        *(uint4*)(dst + n * 128 + q * 8) = o;
    }
}

/* ---------------- input projections ---------------- */
__device__ __forceinline__ void proj_body(int b, const float* __restrict__ hexf, const float* __restrict__ vertf,
                                          const float* __restrict__ edgef,
                                          const float* __restrict__ Wh, const float* __restrict__ bh,
                                          const float* __restrict__ Wv, const float* __restrict__ bv,
                                          const float* __restrict__ We, const float* __restrict__ be,
                                          float* __restrict__ xf) {
    __shared__ float Wl[(9 + 7 + 5) * 128];
    __shared__ float bl[3 * 128];
    int tid = threadIdx.x;
    for (int i = tid; i < 9 * 128; i += 256) Wl[i] = Wh[i];
    for (int i = tid; i < 7 * 128; i += 256) Wl[9 * 128 + i] = Wv[i];
    for (int i = tid; i < 5 * 128; i += 256) Wl[16 * 128 + i] = We[i];
    if (tid < 128) { bl[tid] = bh[tid]; bl[128 + tid] = bv[tid]; bl[256 + tid] = be[tid]; }
    __syncthreads();
    int c = tid & 127;
    for (int n = tid >> 7; n < NNODE; n += 2) {
        const float* f; const float* W; const float* bias; int K;
        if (n < NHEX)              { f = hexf  + ((size_t)b * NHEX  + n) * 9;                  W = Wl;            bias = bl;       K = 9; }
        else if (n < NHEX + NVERT) { f = vertf + ((size_t)b * NVERT + (n - NHEX)) * 7;         W = Wl + 9 * 128;  bias = bl + 128; K = 7; }
        else                       { f = edgef + ((size_t)b * NEDGE + (n - NHEX - NVERT)) * 5; W = Wl + 16 * 128; bias = bl + 256; K = 5; }
        float acc = bias[c];
        for (int k = 0; k < K; ++k) acc += f[k] * W[k * 128 + c];
        xf[((size_t)b * NNODE + n) * HID + c] = acc;
    }
}

/* merged prologue: block 0 topo | 1-15 wvec | 16-75 wp | 76.. proj */
__global__ __launch_bounds__(256) void k_pre(
        int* __restrict__ cst_g, unsigned* __restrict__ pck_g,
        const float* __restrict__ gatW, const float* __restrict__ gatas,
        const float* __restrict__ gatad, ushort_t* __restrict__ wvb, ushort_t* __restrict__ Wp,
        const float* __restrict__ hexf, const float* __restrict__ vertf, const float* __restrict__ edgef,
        const float* __restrict__ Wh, const float* __restrict__ bh,
        const float* __restrict__ Wv, const float* __restrict__ bv,
        const float* __restrict__ We, const float* __restrict__ be,
        float* __restrict__ xf) {
    unsigned kb = blockIdx.x;
    if (kb == 0)       topo_body(cst_g, pck_g);
    else if (kb < 16)  wvec_body((int)kb - 1, gatW, gatas, gatad, wvb);
    else if (kb < 76)  wp_body((int)kb - 16, gatW, Wp);
    else               proj_body((int)kb - 76, hexf, vertf, edgef, Wh, bh, Wv, bv, We, be, xf);
}

/* =========== warp-per-head fused body. KIND0: hex(19); KIND1: edge 18-row quarter; KIND2: vertex 27-row half. */
template<int KIND>
__device__ __forceinline__ void gnn_body(char* smem, int b, int half,
        const float* __restrict__ xf_cur, float* __restrict__ xf_nxt,
        const int* __restrict__ cst_all, const unsigned* __restrict__ pck_all,
        const ushort_t* __restrict__ wvb, const ushort_t* __restrict__ Wp_g,
        const float* __restrict__ gatb_g,
        const float* __restrict__ lg, const float* __restrict__ lb, int l) {
    constexpr int NDT   = (KIND == 0 ? 19 : KIND == 1 ? 18 : 27);
    constexpr int MT    = 2;
    constexpr int NRELF = (KIND == 2 ? 3 : 1);
    constexpr int XR    = (KIND == 0 ? 73 : KIND == 1 ? 72 : 145);
    constexpr int RLMX  = (KIND == 2 ? 99 : XR);
    constexpr int O_ESD = XR * 256;
    constexpr int O_AL  = O_ESD + RLMX * 32;
    constexpr int O_CST = O_AL + MAXE * 16;
    constexpr int O_PCK = O_CST + 32 * 4;

    constexpr int RR_A[3][3] = {{1, 0, 0}, {2, 0, 0}, {0, 3, 4}};
    constexpr int NS_A[3][3] = {{54, 0, 0}, {54, 0, 0}, {19, 72, 54}};
    constexpr int SO_A[3][3] = {{0, 0, 0}, {0, 0, 0}, {0, 19, 91}};

    float*    esd  = (float*)(smem + O_ESD);
    float*    alph = (float*)(smem + O_AL);
    int*      cstL = (int*)(smem + O_CST);
    unsigned* pckL = (unsigned*)(smem + O_PCK);

    const int tid = threadIdx.x, lane = tid & 63, wid = tid >> 6;
    const int kc16 = (lane >> 4) * 16;
    const int doff   = (KIND == 2 ? 91 + half * 27 : 54);
    const int dnode0 = (KIND == 0 ? 0 : KIND == 1 ? 73 + half * 18 : 19 + half * 27);
    const int d0     = (KIND == 1 ? half * 18 : KIND == 2 ? half * 27 : 0);
    const float* xcb = xf_cur + (size_t)b * NNODE * HID;

#define XBA(row, cb) (((row) * 256 + (cb)) ^ (((row) & 7) << 4))

    /* stage all needed x rows, bf16 swizzled */
    for (int i = tid; i < XR * 16; i += 256) {
        int row = i >> 4, q = i & 15;
        int node;
        if (KIND == 0)      node = (row < 54) ? 19 + row : row - 54;
        else if (KIND == 1) node = (row < 54) ? 19 + row : 73 + half * 18 + (row - 54);
        else                node = (row < 19) ? row : (row < 91 ? 73 + (row - 19) : 19 + (row - 91));
        const float* s = xcb + (size_t)node * HID + q * 8;
        float4 u0 = *(const float4*)(s), u1 = *(const float4*)(s + 4);
        uint4 o;
        o.x = pk2(u0.x, u0.y); o.y = pk2(u0.z, u0.w);
        o.z = pk2(u1.x, u1.y); o.w = pk2(u1.z, u1.w);
        *(uint4*)(smem + XBA(row, q * 16)) = o;
    }
    __syncthreads();

    f32x4 acc[MT][8];
#pragma unroll
    for (int mt = 0; mt < MT; ++mt)
#pragma unroll
        for (int nt = 0; nt < 8; ++nt) acc[mt][nt] = (f32x4){0.f, 0.f, 0.f, 0.f};

#pragma unroll
    for (int ri = 0; ri < NRELF; ++ri) {
        const int NS = NS_A[KIND][ri], soff = SO_A[KIND][ri], r = RR_A[KIND][ri];
        const int RL = NS + NDT, lr = l * 5 + r;
        const int jlo = cst_all[r * 73 + d0];

        /* csr window + logits-MFMA (concurrent; barrier after covers both) */
        for (int i = tid; i <= NDT; i += 256) cstL[i] = cst_all[r * 73 + d0 + i] - jlo;
        for (int i = tid; jlo + i < MAXE; i += 256) pckL[i] = pck_all[r * 144 + jlo + i];
        {
            const ushort_t* wv = wvb + (size_t)lr * 2048;
            uint4 bw[4];
#pragma unroll
            for (int ks = 0; ks < 4; ++ks)
                bw[ks] = *(const uint4*)(wv + (lane & 15) * 128 + ks * 32 + (lane >> 4) * 8);
            const int T = (RL + 15) >> 4;
            for (int t = wid; t < T; t += 4) {
                int vrow = t * 16 + (lane & 15);
                int srow = (vrow < NS) ? soff + vrow : ((vrow < RL) ? doff + vrow - NS : doff);
                f32x4 e = (f32x4){0.f, 0.f, 0.f, 0.f};
#pragma unroll
                for (int ks = 0; ks < 4; ++ks) {
                    uint4 av = *(const uint4*)(smem + XBA(srow, ks * 64 + kc16));
                    e = MF(av, bw[ks], e);
                }
#pragma unroll
                for (int g = 0; g < 4; ++g) {
                    float sv = e[g] + __shfl_xor(e[g], 8, 64);
                    int row = t * 16 + (lane >> 4) * 4 + g;
                    if ((lane & 15) < 8 && row < RL) esd[row * 8 + (lane & 15)] = sv;
                }
            }
        }
        __syncthreads();

        /* fused scores + per-(d,h) softmax -> alph (separate buffer) */
        for (int i = tid; i < NDT * 4; i += 256) {
            int d = i >> 2, h = i & 3;
            int s0 = cstL[d], s1 = cstL[d + 1];
            if (s0 == s1) continue;
            float edv = esd[(NS + d) * 8 + 4 + h];
            float m = -1e30f;
            for (int j = s0; j < s1; ++j) {
                float sv = esd[(pckL[j] & 255) * 8 + h] + edv;
                sv = (sv >= 0.f) ? sv : 0.2f * sv;
                alph[j * 4 + h] = sv;
                m = fmaxf(m, sv);
            }
            float sum = 0.f;
            for (int j = s0; j < s1; ++j) {
                float e = (float)(pckL[j] >> 16) * __expf(alph[j * 4 + h] - m);
                alph[j * 4 + h] = e;
                sum += e;
            }
            float inv = 1.f / (sum + 1e-16f);
            for (int j = s0; j < s1; ++j) alph[j * 4 + h] *= inv;
        }
        __syncthreads();

        /* warp = head: build A-fragments in regs, then MFMA vs Wp from L2 */
        {
            const int h = wid;
            const ushort_t* wpH = Wp_g + (size_t)(lr * 4 + h) * 16384;
            uint4 afr[MT][4];
#pragma unroll
            for (int mt = 0; mt < MT; ++mt) {
                int row = mt * 16 + (lane & 15);
                int d = (row < NDT) ? row : NDT - 1;
                int s0 = cstL[d], s1 = cstL[d + 1];
#pragma unroll
                for (int ks = 0; ks < 4; ++ks) {
                    f32x2 a01 = (f32x2){0.f, 0.f}, a23 = (f32x2){0.f, 0.f};
                    f32x2 a45 = (f32x2){0.f, 0.f}, a67 = (f32x2){0.f, 0.f};
                    for (int j = s0; j < s1; ++j) {
                        float al = alph[j * 4 + h];
                        f32x2 al2 = (f32x2){al, al};
                        int srow = soff + (int)(pckL[j] & 255);
                        uint4 xv = *(const uint4*)(smem + XBA(srow, ks * 64 + kc16));
                        a01 += al2 * (f32x2){blo(xv.x), bhi(xv.x)};
                        a23 += al2 * (f32x2){blo(xv.y), bhi(xv.y)};
                        a45 += al2 * (f32x2){blo(xv.z), bhi(xv.z)};
                        a67 += al2 * (f32x2){blo(xv.w), bhi(xv.w)};
                    }
                    uint4 o;
                    o.x = pk2(a01[0], a01[1]); o.y = pk2(a23[0], a23[1]);
                    o.z = pk2(a45[0], a45[1]); o.w = pk2(a67[0], a67[1]);
                    afr[mt][ks] = o;
                }
            }
#pragma unroll
            for (int nt = 0; nt < 8; ++nt) {
                const ushort_t* bp = wpH + (size_t)(nt * 16 + (lane & 15)) * 128 + (lane >> 4) * 8;
                uint4 b0 = *(const uint4*)(bp);
                uint4 b1 = *(const uint4*)(bp + 32);
                uint4 b2 = *(const uint4*)(bp + 64);
                uint4 b3 = *(const uint4*)(bp + 96);
#pragma unroll
                for (int mt = 0; mt < MT; ++mt) {
                    f32x4 a = acc[mt][nt];
                    a = MF(afr[mt][0], b0, a);
                    a = MF(afr[mt][1], b1, a);
                    a = MF(afr[mt][2], b2, a);
                    a = MF(afr[mt][3], b3, a);
                    acc[mt][nt] = a;
                }
            }
        }
        __syncthreads();   /* alph/esd reuse + (last rel) X death */
    }

    /* ---- deterministic cross-head reduce into lnb (overlays X) ---- */
    float* lnb = (float*)smem;
    for (int i = tid; i < NDT * 128; i += 256) {
        int d = i >> 7, c = i & 127;
        float bs = 0.f;
#pragma unroll
        for (int ri = 0; ri < NRELF; ++ri)
            bs += gatb_g[(size_t)(l * 5 + RR_A[KIND][ri]) * 128 + c];
        lnb[i] = bs + xcb[(size_t)(dnode0 + d) * HID + c];
    }
    __syncthreads();
    for (int p = 0; p < 4; ++p) {
#pragma unroll
        for (int mt = 0; mt < MT; ++mt)
#pragma unroll
            for (int nt = 0; nt < 8; ++nt) {
                if ((((nt >> 1) - wid) & 3) == p) {
#pragma unroll
                    for (int g = 0; g < 4; ++g) {
                        int row = mt * 16 + (lane >> 4) * 4 + g;
                        int col = nt * 16 + (lane & 15);
                        if (row < NDT) lnb[row * 128 + col] += 0.25f * acc[mt][nt][g];
                    }
                }
            }
        __syncthreads();
    }

    /* ---- LN + relu -> xf_nxt ---- */
    for (int d = wid; d < NDT; d += 4) {
        float a0 = lnb[d * 128 + lane];
        float a1 = lnb[d * 128 + 64 + lane];
        float s = a0 + a1;
        for (int m = 1; m < 64; m <<= 1) s += __shfl_xor(s, m, 64);
        float mu = s * (1.f / 128.f);
        float dv0 = a0 - mu, dv1 = a1 - mu;
        float q = dv0 * dv0 + dv1 * dv1;
        for (int m = 1; m < 64; m <<= 1) q += __shfl_xor(q, m, 64);
        float rs = rsqrtf(q * (1.f / 128.f) + 1e-5f);
        float o0 = fmaxf(dv0 * rs * lg[lane] + lb[lane], 0.f);
        float o1 = fmaxf(dv1 * rs * lg[64 + lane] + lb[64 + lane], 0.f);
        size_t gi = ((size_t)b * NNODE + dnode0 + d) * 128;
        xf_nxt[gi + lane] = o0;
        xf_nxt[gi + 64 + lane] = o1;
    }
#undef XBA
}

/* max LDS = KIND2: 145*256 + 99*32 + 144*16 + 128 + 576 = 43296 */
#define SMEM_TOT 43296

__global__ __launch_bounds__(256, 3) void k_layer(
        const float* __restrict__ xf_cur, float* __restrict__ xf_nxt,
        const int* __restrict__ cst, const unsigned* __restrict__ pck,
        const ushort_t* __restrict__ wvb, const ushort_t* __restrict__ Wp,
        const float* __restrict__ gatb, const float* __restrict__ lngp,
        const float* __restrict__ lnbp, int l) {
    extern __shared__ uint4 smem_u4[];
    char* smem = (char*)smem_u4;
    unsigned kb = blockIdx.x;
    if (kb < 2048)
        gnn_body<2>(smem, (int)(kb >> 1), (int)(kb & 1), xf_cur, xf_nxt, cst, pck, wvb, Wp, gatb,
                    lngp + (size_t)(l * 3 + 1) * 128, lnbp + (size_t)(l * 3 + 1) * 128, l);
    else if (kb < 6144) {
        unsigned t = kb - 2048;
        gnn_body<1>(smem, (int)(t >> 2), (int)(t & 3), xf_cur, xf_nxt, cst, pck, wvb, Wp, gatb,
                    lngp + (size_t)(l * 3 + 2) * 128, lnbp + (size_t)(l * 3 + 2) * 128, l);
    } else
        gnn_body<0>(smem, (int)(kb - 6144), 0, xf_cur, xf_nxt, cst, pck, wvb, Wp, gatb,
                    lngp + (size_t)(l * 3 + 0) * 128, lnbp + (size_t)(l * 3 + 0) * 128, l);
}

/* ---------------- fused head: pools + player gather + MLP1 + MLP2 ---------------- */
__global__ __launch_bounds__(128) void k_head(const float* __restrict__ x, const float* __restrict__ playerf,
                                              const int* __restrict__ curp,
                                              const float* __restrict__ W1, const float* __restrict__ b1,
                                              const float* __restrict__ W2, const float* __restrict__ b2,
                                              float* __restrict__ out) {
    __shared__ float fs[POOLD];
    __shared__ float h1s[HID];
    int b = blockIdx.x, c = threadIdx.x;
    const float* xb = x + (size_t)b * NNODE * HID;
    float s0 = 0.f, s1 = 0.f, s2 = 0.f;
    for (int n = 0; n < NHEX; ++n)             s0 += xb[n * HID + c];
    for (int n = NHEX; n < NHEX + NVERT; ++n)  s1 += xb[n * HID + c];
    for (int n = NHEX + NVERT; n < NNODE; ++n) s2 += xb[n * HID + c];
    fs[c]       = s0 * (1.f / 19.f);
    fs[128 + c] = s1 * (1.f / 54.f);
    fs[256 + c] = s2 * (1.f / 72.f);
    if (c < FPLY) fs[384 + c] = playerf[((size_t)b * 4 + curp[b]) * FPLY + c];
    __syncthreads();
    float a = b1[c];
    for (int k = 0; k < POOLD; ++k) a += fs[k] * W1[(size_t)k * HID + c];
    h1s[c] = fmaxf(a, 0.f);
    __syncthreads();
    float o0 = b2[c], o1 = b2[128 + c];
    for (int j = 0; j < HID; ++j) {
        float hv = h1s[j];
        o0 += hv * W2[(size_t)j * OUTD + c];
        o1 += hv * W2[(size_t)j * OUTD + 128 + c];
    }
    out[(size_t)b * OUTD + c] = o0;
    out[(size_t)b * OUTD + 128 + c] = o1;
}

/* ---------------- workspace layout ---------------- */
static constexpr size_t alignUp(size_t v) { return (v + 255) & ~(size_t)255; }
static constexpr size_t OFF_CST  = 0;
static constexpr size_t OFF_PCK  = alignUp(OFF_CST + 5 * 73 * 4);
static constexpr size_t OFF_WVB  = alignUp(OFF_PCK + 5 * 144 * 4);
static constexpr size_t OFF_WP   = alignUp(OFF_WVB + (size_t)15 * 16 * 128 * 2);
static constexpr size_t OFF_XA   = alignUp(OFF_WP + (size_t)15 * 4 * 128 * 128 * 2);
static constexpr size_t OFF_XB2  = OFF_XA + (size_t)NB * NNODE * HID * 4;

extern "C" void kernel_launch(void* const* d_in, const int* in_sizes, int n_in,
                              void* d_out, int out_size, void* d_ws, size_t ws_size,
                              hipStream_t stream) {
    (void)in_sizes; (void)n_in; (void)out_size; (void)ws_size;
    const float* hexf   = (const float*)d_in[0];
    const float* vertf  = (const float*)d_in[1];
    const float* edgef  = (const float*)d_in[2];
    const float* playerf= (const float*)d_in[3];
    const float* inhW   = (const float*)d_in[4];
    const float* inhb   = (const float*)d_in[5];
    const float* invW   = (const float*)d_in[6];
    const float* invb   = (const float*)d_in[7];
    const float* ineW   = (const float*)d_in[8];
    const float* ineb   = (const float*)d_in[9];
    const float* gatW   = (const float*)d_in[10];
    const float* gatas  = (const float*)d_in[11];
    const float* gatad  = (const float*)d_in[12];
    const float* gatb   = (const float*)d_in[13];
    const float* lngp   = (const float*)d_in[14];
    const float* lnbp   = (const float*)d_in[15];
    const float* mW1    = (const float*)d_in[16];
    const float* mb1    = (const float*)d_in[17];
    const float* mW2    = (const float*)d_in[18];
    const float* mb2    = (const float*)d_in[19];
    const int*   curp   = (const int*)d_in[20];
    float* out = (float*)d_out;

    char* ws = (char*)d_ws;
    int* cst        = (int*)(ws + OFF_CST);
    unsigned* pck   = (unsigned*)(ws + OFF_PCK);
    ushort_t* wvb   = (ushort_t*)(ws + OFF_WVB);
    ushort_t* Wp    = (ushort_t*)(ws + OFF_WP);
    float* xfA      = (float*)(ws + OFF_XA);
    float* xfB      = (float*)(ws + OFF_XB2);

    k_pre<<<76 + NB, 256, 0, stream>>>(cst, pck, gatW, gatas, gatad, wvb, Wp,
                                       hexf, vertf, edgef, inhW, inhb, invW, invb, ineW, ineb, xfA);

    for (int l = 0; l < NLAYERS; ++l) {
        const float* cur = (l & 1) ? xfB : xfA;
        float* nxt = (l & 1) ? xfA : xfB;
        k_layer<<<7168, 256, SMEM_TOT, stream>>>(cur, nxt, cst, pck, wvb, Wp, gatb, lngp, lnbp, l);
    }

    k_head<<<NB, 128, 0, stream>>>(xfB, playerf, curp, mW1, mb1, mW2, mb2, out);
}

// Round 8
// 918.739 us; speedup vs baseline: 1.3848x; 1.3848x over previous
//
#include <hip/hip_runtime.h>
#include <math.h>

#define NB 1024
#define NHEX 19
#define NVERT 54
#define NEDGE 72
#define NNODE 145   /* hex[0,19) vert[19,73) edge[73,145) */
#define HID 128
#define NLAYERS 3
#define MAXE 144
#define OUTD 256
#define FPLY 14
#define POOLD 398

typedef unsigned short ushort_t;
typedef short bf16x8 __attribute__((ext_vector_type(8)));
typedef float f32x4 __attribute__((ext_vector_type(4)));
typedef float f32x2 __attribute__((ext_vector_type(2)));

static __device__ __forceinline__ float bf2f(ushort_t u) {
    return __uint_as_float(((unsigned int)u) << 16);
}
static __device__ __forceinline__ ushort_t f2bf(float f) {
    unsigned int u = __float_as_uint(f);
    return (ushort_t)((u + 0x7fffu + ((u >> 16) & 1u)) >> 16);
}
/* packed f32->bf16x2 via HW cvt (RNE) */
static __device__ __forceinline__ unsigned pk2(float lo, float hi) {
    unsigned r;
    asm("v_cvt_pk_bf16_f32 %0, %1, %2" : "=v"(r) : "v"(lo), "v"(hi));
    return r;
}
static __device__ __forceinline__ float blo(unsigned u) { return __uint_as_float(u << 16); }
static __device__ __forceinline__ float bhi(unsigned u) { return __uint_as_float(u & 0xffff0000u); }
static __device__ __forceinline__ f32x4 MF(uint4 a, uint4 b, f32x4 c) {
    return __builtin_amdgcn_mfma_f32_16x16x32_bf16(
        __builtin_bit_cast(bf16x8, a), __builtin_bit_cast(bf16x8, b), c, 0, 0, 0);
}

/* ================= topology (numpy RandomState(0) replica) + dedup CSR ============ */
__device__ __forceinline__ void topo_body(int* __restrict__ cst_g, unsigned* __restrict__ pck_g) {
    __shared__ unsigned mt[624];
    __shared__ int t6[624];
    __shared__ int sc[624];
    __shared__ int hv[114], v0a[72], v1a[72];
    __shared__ int cnt[80];
    __shared__ int dloc[73 * 24];
    __shared__ int J186;
    const int tid = threadIdx.x;

    if (tid == 0) {
        unsigned s = 0u;
        for (int i = 0; i < 624; ++i) { mt[i] = s; s = 1812433253u * (s ^ (s >> 30)) + (unsigned)i + 1u; }
    }
    __syncthreads();
    {
        unsigned a = 0, bb = 0, c = 0;
        if (tid < 227) { a = mt[tid]; bb = mt[tid + 1]; c = mt[tid + 397]; }
        __syncthreads();
        if (tid < 227) {
            unsigned y = (a & 0x80000000u) | (bb & 0x7fffffffu);
            mt[tid] = c ^ (y >> 1) ^ ((bb & 1u) ? 0x9908b0dfu : 0u);
        }
        __syncthreads();
    }
    {
        int i = 227 + tid;
        unsigned a = 0, bb = 0, c = 0;
        if (tid < 227) { a = mt[i]; bb = mt[i + 1]; c = mt[i - 227]; }
        __syncthreads();
        if (tid < 227) {
            unsigned y = (a & 0x80000000u) | (bb & 0x7fffffffu);
            mt[i] = c ^ (y >> 1) ^ ((bb & 1u) ? 0x9908b0dfu : 0u);
        }
        __syncthreads();
    }
    {
        int i = 454 + tid;
        unsigned a = 0, bb = 0, c = 0;
        if (tid < 170) { a = mt[i]; bb = mt[(i + 1) % 624]; c = mt[i - 227]; }
        __syncthreads();
        if (tid < 170) {
            unsigned y = (a & 0x80000000u) | (bb & 0x7fffffffu);
            mt[i] = c ^ (y >> 1) ^ ((bb & 1u) ? 0x9908b0dfu : 0u);
        }
        __syncthreads();
    }
    for (int i = tid; i < 624; i += 256) {
        unsigned y = mt[i];
        y ^= y >> 11; y ^= (y << 7) & 0x9d2c5680u; y ^= (y << 15) & 0xefc60000u; y ^= y >> 18;
        t6[i] = (int)(y & 63u);
    }
    __syncthreads();
#define SCAN624()                                                          \
    for (int off = 1; off < 624; off <<= 1) {                              \
        int v0_ = 0, v1_ = 0, v2_ = 0;                                     \
        int i0 = tid, i1 = tid + 256, i2 = tid + 512;                      \
        if (i0 >= off) v0_ = sc[i0 - off];                                 \
        if (i1 >= off) v1_ = sc[i1 - off];                                 \
        if (i2 < 624 && i2 >= off) v2_ = sc[i2 - off];                     \
        __syncthreads();                                                   \
        sc[i0] += v0_; sc[i1] += v1_;                                      \
        if (i2 < 624) sc[i2] += v2_;                                       \
        __syncthreads();                                                   \
    }
    for (int i = tid; i < 624; i += 256) sc[i] = (t6[i] <= 53) ? 1 : 0;
    __syncthreads();
    SCAN624();
    for (int i = tid; i < 624; i += 256) {
        if (t6[i] <= 53) {
            int k = sc[i];
            if (k <= 114) hv[k - 1] = t6[i];
            else if (k <= 186) v0a[k - 115] = t6[i];
            if (k == 186) J186 = i;
        }
    }
    __syncthreads();
    int Jcap = J186;
    for (int i = tid; i < 624; i += 256) sc[i] = (i > Jcap && t6[i] <= 52) ? 1 : 0;
    __syncthreads();
    SCAN624();
    for (int i = tid; i < 624; i += 256) {
        if (i > Jcap && t6[i] <= 52) {
            int k = sc[i];
            if (k <= 72) v1a[k - 1] = (v0a[k - 1] + 1 + t6[i]) % 54;
        }
    }
    __syncthreads();
#undef SCAN624
    /* dedup CSR per relation: pck = s | d<<8 | mult<<16 */
    const int En[5] = {114, 114, 144, 144, 144};
    const int Ndn[5] = {54, 19, 72, 54, 54};
    for (int r = 0; r < 5; ++r) {
        int E = En[r], Nd = Ndn[r];
        int myc = 0;
        if (tid < Nd) {
            int* ss = dloc + tid * 24;
            for (int k = 0; k < E; ++k) {
                int s, d;
                if (r == 0)      { s = k / 6; d = hv[k]; }
                else if (r == 1) { s = hv[k]; d = k / 6; }
                else if (r == 2) { s = (k & 1) ? v1a[k >> 1] : v0a[k >> 1]; d = k >> 1; }
                else if (r == 3) { s = k >> 1; d = (k & 1) ? v1a[k >> 1] : v0a[k >> 1]; }
                else             { s = (k < 72) ? v0a[k] : v1a[k - 72]; d = (k < 72) ? v1a[k] : v0a[k - 72]; }
                if (d != tid) continue;
                int f = -1;
                for (int i2 = 0; i2 < myc; ++i2) if ((ss[i2] & 255) == s) { f = i2; break; }
                if (f >= 0) ss[f] += 1 << 16;
                else { if (myc < 24) { ss[myc++] = s | (1 << 16); } }
            }
            cnt[tid] = myc;
        }
        __syncthreads();
        for (int off = 1; off < 128; off <<= 1) {
            int v = 0;
            if (tid < Nd && tid >= off) v = cnt[tid - off];
            __syncthreads();
            if (tid < Nd && tid >= off) cnt[tid] += v;
            __syncthreads();
        }
        if (tid < Nd) {
            int st = cnt[tid] - myc;
            cst_g[r * 73 + tid] = st;
            if (tid == Nd - 1) cst_g[r * 73 + Nd] = cnt[tid];
            int* ss = dloc + tid * 24;
            for (int i2 = 0; i2 < myc; ++i2)
                pck_g[r * 144 + st + i2] =
                    (unsigned)((ss[i2] & 255) | (tid << 8) | ((ss[i2] >> 16) << 16));
        }
        __syncthreads();
    }
}

/* -------- attention vectors, packed 16-vec tile: vec h=was_hi, 4+h=wad_hi, 8+h=was_lo, 12+h=wad_lo -- */
__device__ __forceinline__ void wvec_body(int lr, const float* __restrict__ gat_W,
                                          const float* __restrict__ gat_asrc,
                                          const float* __restrict__ gat_adst,
                                          ushort_t* __restrict__ wvb) {
    __shared__ float as_s[512], ad_s[512];
    int tid = threadIdx.x;
    for (int i = tid; i < 512; i += 256) {
        as_s[i] = gat_asrc[(size_t)lr * 512 + i];
        ad_s[i] = gat_adst[(size_t)lr * 512 + i];
    }
    __syncthreads();
    ushort_t* wb = wvb + (size_t)lr * 2048;
    const float* W = gat_W + (size_t)lr * 128 * 512;
    int t127 = tid & 127, rhalf = tid >> 7;
    int h = t127 >> 5, c4 = t127 & 31;
    for (int k0 = 0; k0 < 128; k0 += 2) {
        int k = k0 + rhalf;
        float4 wv4 = *(const float4*)(W + (size_t)k * 512 + h * 128 + c4 * 4);
        const float* a = as_s + h * 128 + c4 * 4;
        const float* dd = ad_s + h * 128 + c4 * 4;
        float pa = wv4.x * a[0] + wv4.y * a[1] + wv4.z * a[2] + wv4.w * a[3];
        float pd = wv4.x * dd[0] + wv4.y * dd[1] + wv4.z * dd[2] + wv4.w * dd[3];
        for (int m = 1; m < 32; m <<= 1) { pa += __shfl_xor(pa, m, 64); pd += __shfl_xor(pd, m, 64); }
        if (c4 == 0) {
            ushort_t pah = f2bf(pa), pdh = f2bf(pd);
            ushort_t pal = f2bf(pa - bf2f(pah)), pdl = f2bf(pd - bf2f(pdh));
            wb[h * 128 + k] = pah;        wb[(4 + h) * 128 + k] = pdh;
            wb[(8 + h) * 128 + k] = pal;  wb[(12 + h) * 128 + k] = pdl;
        }
    }
}

/* -------- Wp[lr][h][n][k] = bf16(gat_W[lr][k][h*128+n]) -------- */
__device__ __forceinline__ void wp_body(int lrh, const float* __restrict__ gat_W, ushort_t* __restrict__ Wp) {
    __shared__ ushort_t tr[128 * 130];
    int lr = lrh >> 2, h = lrh & 3;
    const float* Wsrc = gat_W + (size_t)lr * 128 * 512 + h * 128;
    for (int i = threadIdx.x; i < 128 * 32; i += 256) {
        int k = i >> 5, q = i & 31;
        float4 v = *(const float4*)(Wsrc + (size_t)k * 512 + q * 4);
        int n = q * 4;
        tr[(n + 0) * 130 + k] = f2bf(v.x);
        tr[(n + 1) * 130 + k] = f2bf(v.y);
        tr[(n + 2) * 130 + k] = f2bf(v.z);
        tr[(n + 3) * 130 + k] = f2bf(v.w);
    }
    __syncthreads();
    ushort_t* dst = Wp + (size_t)lrh * 128 * 128;
    for (int i = threadIdx.x; i < 128 * 16; i += 256) {
        int n = i >> 4, q = i & 15;
        const ushort_t* s = tr + n * 130 + q * 8;
        uint4 o;
        o.x = (unsigned)s[0] | ((unsigned)s[1] << 16);
        o.y = (unsigned)s[2] | ((unsigned)s[3] << 16);
        o.z = (unsigned)s[4] | ((unsigned)s[5] << 16);
        o.w = (unsigned)s[6] | ((unsigned)s[7] << 16);
        *(uint4*)(dst + n * 128 + q * 8) = o;
    }
}

/* ---------------- input projections -> bf16 x ---------------- */
__device__ __forceinline__ void proj_body(int b, const float* __restrict__ hexf, const float* __restrict__ vertf,
                                          const float* __restrict__ edgef,
                                          const float* __restrict__ Wh, const float* __restrict__ bh,
                                          const float* __restrict__ Wv, const float* __restrict__ bv,
                                          const float* __restrict__ We, const float* __restrict__ be,
                                          ushort_t* __restrict__ xb) {
    __shared__ float Wl[(9 + 7 + 5) * 128];
    __shared__ float bl[3 * 128];
    int tid = threadIdx.x;
    for (int i = tid; i < 9 * 128; i += 256) Wl[i] = Wh[i];
    for (int i = tid; i < 7 * 128; i += 256) Wl[9 * 128 + i] = Wv[i];
    for (int i = tid; i < 5 * 128; i += 256) Wl[16 * 128 + i] = We[i];
    if (tid < 128) { bl[tid] = bh[tid]; bl[128 + tid] = bv[tid]; bl[256 + tid] = be[tid]; }
    __syncthreads();
    int c = tid & 127;
    for (int n = tid >> 7; n < NNODE; n += 2) {
        const float* f; const float* W; const float* bias; int K;
        if (n < NHEX)              { f = hexf  + ((size_t)b * NHEX  + n) * 9;                  W = Wl;            bias = bl;       K = 9; }
        else if (n < NHEX + NVERT) { f = vertf + ((size_t)b * NVERT + (n - NHEX)) * 7;         W = Wl + 9 * 128;  bias = bl + 128; K = 7; }
        else                       { f = edgef + ((size_t)b * NEDGE + (n - NHEX - NVERT)) * 5; W = Wl + 16 * 128; bias = bl + 256; K = 5; }
        float acc = bias[c];
        for (int k = 0; k < K; ++k) acc += f[k] * W[k * 128 + c];
        xb[((size_t)b * NNODE + n) * HID + c] = f2bf(acc);
    }
}

/* merged prologue: block 0 topo | 1-15 wvec | 16-75 wp | 76.. proj */
__global__ __launch_bounds__(256) void k_pre(
        int* __restrict__ cst_g, unsigned* __restrict__ pck_g,
        const float* __restrict__ gatW, const float* __restrict__ gatas,
        const float* __restrict__ gatad, ushort_t* __restrict__ wvb, ushort_t* __restrict__ Wp,
        const float* __restrict__ hexf, const float* __restrict__ vertf, const float* __restrict__ edgef,
        const float* __restrict__ Wh, const float* __restrict__ bh,
        const float* __restrict__ Wv, const float* __restrict__ bv,
        const float* __restrict__ We, const float* __restrict__ be,
        ushort_t* __restrict__ xb) {
    unsigned kb = blockIdx.x;
    if (kb == 0)       topo_body(cst_g, pck_g);
    else if (kb < 16)  wvec_body((int)kb - 1, gatW, gatas, gatad, wvb);
    else if (kb < 76)  wp_body((int)kb - 16, gatW, Wp);
    else               proj_body((int)kb - 76, hexf, vertf, edgef, Wh, bh, Wv, bv, We, be, xb);
}

/* =========== fused per-(layer, dst-type) body: logits-MFMA + fused softmax + y-build + MFMA2 ===== */
template<int KIND>
__device__ __forceinline__ void gnn_body(char* smem, int b,
        const ushort_t* __restrict__ xb_cur, ushort_t* __restrict__ xb_nxt,
        const int* __restrict__ cst_all, const unsigned* __restrict__ pck_all,
        const ushort_t* __restrict__ wvb, const ushort_t* __restrict__ Wp_g,
        const float* __restrict__ gatb_g,
        const float* __restrict__ lg, const float* __restrict__ lb, int l) {
    constexpr int ND    = (KIND == 0 ? 19 : KIND == 1 ? 72 : 54);
    constexpr int DB    = (KIND == 0 ? 0 : KIND == 1 ? 73 : 19);
    constexpr int NSMAX = (KIND == 2 ? 72 : 54);
    constexpr int NRELF = (KIND == 2 ? 3 : 1);
    constexpr int MT    = (ND + 15) / 16;
    constexpr int O_Y   = (ND + NSMAX) * 256;                 /* KIND2: y after src; else y overlays dst */
    constexpr int YSZ   = (KIND == 2 ? ND * 256 : 0);
    constexpr int O_ESD = O_Y + YSZ;
    constexpr int O_AL  = O_ESD + 4032;
    constexpr int O_CST = O_AL + 2304;
    constexpr int O_PCK = O_CST + 304;

    constexpr int NS_A[3][3] = {{54, 0, 0}, {54, 0, 0}, {19, 72, 54}};
    constexpr int SB_A[3][3] = {{19, 0, 0}, {19, 0, 0}, {0, 73, 19}};
    constexpr int RR_A[3][3] = {{1, 0, 0}, {2, 0, 0}, {0, 3, 4}};

    float*    esd  = (float*)(smem + O_ESD);
    float*    alph = (float*)(smem + O_AL);
    int*      cstL = (int*)(smem + O_CST);
    unsigned* pckL = (unsigned*)(smem + O_PCK);

    const int tid = threadIdx.x, lane = tid & 63, wid = tid >> 6;
    const int nr0 = wid * 32 + (lane & 15);
    const int kc16 = (lane >> 4) * 16;
    const ushort_t* xcb = xb_cur + (size_t)b * NNODE * HID;

#define XBA(row, cb) (((row) * 256 + (cb)) ^ (((row) & 7) << 4))
#define YBA(row, cb) ((KIND == 2 ? O_Y : 0) + ((((row) * 256) + (cb)) ^ (((row) & 7) << 4)))

    /* stage dst rows [0, ND) bf16 swizzled — straight copy */
    for (int i = tid; i < ND * 16; i += 256) {
        int row = i >> 4, q = i & 15;
        uint4 o = *(const uint4*)(xcb + (size_t)(DB + row) * HID + q * 8);
        *(uint4*)(smem + XBA(row, q * 16)) = o;
    }

    f32x4 acc[MT][2];
#pragma unroll
    for (int mt = 0; mt < MT; ++mt) {
        acc[mt][0] = (f32x4){0.f, 0.f, 0.f, 0.f};
        acc[mt][1] = (f32x4){0.f, 0.f, 0.f, 0.f};
    }

#pragma unroll
    for (int ri = 0; ri < NRELF; ++ri) {
        const int NS = NS_A[KIND][ri], SBG = SB_A[KIND][ri], r = RR_A[KIND][ri];
        const bool SELF = (KIND == 2 && ri == 2);   /* rel4: src rows == dst rows */
        const int RL = SELF ? ND : ND + NS;         /* rows needing logits */
        const int lr = l * 5 + r;

        if (!SELF)
            for (int i = tid; i < NS * 16; i += 256) {
                int row = ND + (i >> 4), q = i & 15;
                uint4 o = *(const uint4*)(xcb + (size_t)(SBG + (i >> 4)) * HID + q * 8);
                *(uint4*)(smem + XBA(row, q * 16)) = o;
            }
        for (int i = tid; i <= ND; i += 256) cstL[i] = cst_all[r * 73 + i];
        for (int i = tid; i < 144; i += 256) pckL[i] = pck_all[r * 144 + i];
        __syncthreads();

        /* logits-MFMA: one packed B tile (hi+lo summed via shfl_xor 8) */
        {
            const ushort_t* wv = wvb + (size_t)lr * 2048;
            uint4 bw[4];
#pragma unroll
            for (int ks = 0; ks < 4; ++ks)
                bw[ks] = *(const uint4*)(wv + (lane & 15) * 128 + ks * 32 + (lane >> 4) * 8);
            const int T = (RL + 15) >> 4;
            for (int t = wid; t < T; t += 4) {
                f32x4 e = (f32x4){0.f, 0.f, 0.f, 0.f};
                int arow = t * 16 + (lane & 15);
#pragma unroll
                for (int ks = 0; ks < 4; ++ks) {
                    uint4 av = *(const uint4*)(smem + XBA(arow, ks * 64 + kc16));
                    e = MF(av, bw[ks], e);
                }
#pragma unroll
                for (int g = 0; g < 4; ++g) {
                    float sv = e[g] + __shfl_xor(e[g], 8, 64);
                    int row = t * 16 + (lane >> 4) * 4 + g;
                    if ((lane & 15) < 8 && row < RL) esd[row * 8 + (lane & 15)] = sv;
                }
            }
        }
        __syncthreads();

        /* fused scores + per-(d,h) softmax -> alph */
        for (int i = tid; i < ND * 4; i += 256) {
            int d = i >> 2, h = i & 3;
            int s0 = cstL[d], s1 = cstL[d + 1];
            if (s0 == s1) continue;
            float edv = esd[d * 8 + 4 + h];
            float m = -1e30f;
            for (int j = s0; j < s1; ++j) {
                int s = pckL[j] & 255;
                float sv = esd[(SELF ? s : ND + s) * 8 + h] + edv;
                sv = (sv >= 0.f) ? sv : 0.2f * sv;
                alph[j * 4 + h] = sv;
                m = fmaxf(m, sv);
            }
            float sum = 0.f;
            for (int j = s0; j < s1; ++j) {
                float e = (float)(pckL[j] >> 16) * __expf(alph[j * 4 + h] - m);
                alph[j * 4 + h] = e;
                sum += e;
            }
            float inv = 1.f / (sum + 1e-16f);
            for (int j = s0; j < s1; ++j) alph[j * 4 + h] *= inv;
        }
        __syncthreads();

        /* heads: y-build (packed f32x2 FMA) + MFMA2 */
        for (int h = 0; h < 4; ++h) {
            for (int i = tid; i < ND * 16; i += 256) {
                int d = i >> 4, c8 = i & 15;
                int s0 = cstL[d], s1 = cstL[d + 1];
                f32x2 a01 = (f32x2){0.f, 0.f}, a23 = (f32x2){0.f, 0.f};
                f32x2 a45 = (f32x2){0.f, 0.f}, a67 = (f32x2){0.f, 0.f};
                for (int j = s0; j < s1; ++j) {
                    float al = alph[j * 4 + h];
                    f32x2 al2 = (f32x2){al, al};
                    int s = pckL[j] & 255;
                    int srow = SELF ? s : ND + s;
                    uint4 xv = *(const uint4*)(smem + XBA(srow, c8 * 16));
                    a01 += al2 * (f32x2){blo(xv.x), bhi(xv.x)};
                    a23 += al2 * (f32x2){blo(xv.y), bhi(xv.y)};
                    a45 += al2 * (f32x2){blo(xv.z), bhi(xv.z)};
                    a67 += al2 * (f32x2){blo(xv.w), bhi(xv.w)};
                }
                uint4 o;
                o.x = pk2(a01[0], a01[1]); o.y = pk2(a23[0], a23[1]);
                o.z = pk2(a45[0], a45[1]); o.w = pk2(a67[0], a67[1]);
                *(uint4*)(smem + YBA(d, c8 * 16)) = o;
            }
            /* B fragments loaded after y-build issue (short live range) */
            const ushort_t* wpH = Wp_g + (size_t)(lr * 4 + h) * 16384;
            uint4 bfr[8];
#pragma unroll
            for (int nt = 0; nt < 2; ++nt)
#pragma unroll
                for (int ks = 0; ks < 4; ++ks)
                    bfr[nt * 4 + ks] = *(const uint4*)(wpH + (size_t)(nr0 + nt * 16) * 128 + ks * 32 + (lane >> 4) * 8);
            __syncthreads();
#pragma unroll
            for (int ks = 0; ks < 4; ++ks)
#pragma unroll
                for (int mt = 0; mt < MT; ++mt) {
                    int arow = mt * 16 + (lane & 15);
                    if (arow >= ND) arow = ND - 1;   /* clamp: garbage rows discarded at write */
                    uint4 av = *(const uint4*)(smem + YBA(arow, ks * 64 + kc16));
                    acc[mt][0] = MF(av, bfr[ks], acc[mt][0]);
                    acc[mt][1] = MF(av, bfr[4 + ks], acc[mt][1]);
                }
            __syncthreads();
        }
    }

    /* epilogue: bias + residual(bf16 global) + LN + relu -> xb_nxt */
    float bn0 = 0.f, bn1 = 0.f;
#pragma unroll
    for (int ri = 0; ri < NRELF; ++ri) {
        const float* bb = gatb_g + (size_t)(l * 5 + RR_A[KIND][ri]) * 128;
        bn0 += bb[nr0]; bn1 += bb[nr0 + 16];
    }
    float* lnb_s = (float*)smem;
#pragma unroll
    for (int mt = 0; mt < MT; ++mt)
#pragma unroll
        for (int nt = 0; nt < 2; ++nt) {
            int n = nr0 + nt * 16;
            float bn = nt ? bn1 : bn0;
#pragma unroll
            for (int g = 0; g < 4; ++g) {
                int row = mt * 16 + (lane >> 4) * 4 + g;
                if (row < ND)
                    lnb_s[row * 128 + n] = 0.25f * acc[mt][nt][g] + bn
                        + bf2f(xcb[(size_t)(DB + row) * HID + n]);
            }
        }
    __syncthreads();
    for (int d = wid; d < ND; d += 4) {
        float a0 = lnb_s[d * 128 + lane];
        float a1 = lnb_s[d * 128 + 64 + lane];
        float s = a0 + a1;
        for (int m = 1; m < 64; m <<= 1) s += __shfl_xor(s, m, 64);
        float mu = s * (1.f / 128.f);
        float dv0 = a0 - mu, dv1 = a1 - mu;
        float q = dv0 * dv0 + dv1 * dv1;
        for (int m = 1; m < 64; m <<= 1) q += __shfl_xor(q, m, 64);
        float rs = rsqrtf(q * (1.f / 128.f) + 1e-5f);
        float o0 = fmaxf(dv0 * rs * lg[lane] + lb[lane], 0.f);
        float o1 = fmaxf(dv1 * rs * lg[64 + lane] + lb[64 + lane], 0.f);
        size_t gi = ((size_t)b * NNODE + DB + d) * 128;
        xb_nxt[gi + lane] = f2bf(o0);
        xb_nxt[gi + 64 + lane] = f2bf(o1);
    }
#undef XBA
#undef YBA
}

/* max LDS = KIND2: 180*256 + 4032 + 2304 + 304 + 576 = 53296 */
#define SMEM_TOT 53296

__global__ __launch_bounds__(256, 2) void k_layer(
        const ushort_t* __restrict__ xb_cur, ushort_t* __restrict__ xb_nxt,
        const int* __restrict__ cst, const unsigned* __restrict__ pck,
        const ushort_t* __restrict__ wvb, const ushort_t* __restrict__ Wp,
        const float* __restrict__ gatb, const float* __restrict__ lngp,
        const float* __restrict__ lnbp, int l) {
    extern __shared__ uint4 smem_u4[];
    char* smem = (char*)smem_u4;
    unsigned kb = blockIdx.x;
    if (kb < NB)
        gnn_body<2>(smem, (int)kb, xb_cur, xb_nxt, cst, pck, wvb, Wp, gatb,
                    lngp + (size_t)(l * 3 + 1) * 128, lnbp + (size_t)(l * 3 + 1) * 128, l);
    else if (kb < 2 * NB)
        gnn_body<1>(smem, (int)(kb - NB), xb_cur, xb_nxt, cst, pck, wvb, Wp, gatb,
                    lngp + (size_t)(l * 3 + 2) * 128, lnbp + (size_t)(l * 3 + 2) * 128, l);
    else
        gnn_body<0>(smem, (int)(kb - 2 * NB), xb_cur, xb_nxt, cst, pck, wvb, Wp, gatb,
                    lngp + (size_t)(l * 3 + 0) * 128, lnbp + (size_t)(l * 3 + 0) * 128, l);
}

/* ---------------- fused head: pools + player gather + MLP1 + MLP2 (256 threads) ---------------- */
__global__ __launch_bounds__(256) void k_head(const ushort_t* __restrict__ xb, const float* __restrict__ playerf,
                                              const int* __restrict__ curp,
                                              const float* __restrict__ W1, const float* __restrict__ b1,
                                              const float* __restrict__ W2, const float* __restrict__ b2,
                                              float* __restrict__ out) {
    __shared__ float fs[POOLD];
    __shared__ float ps[256];
    __shared__ float h1s[HID];
    int b = blockIdx.x, t = threadIdx.x;
    int c = t & 127, half = t >> 7;
    const ushort_t* xbb = xb + (size_t)b * NNODE * HID;
    float s0 = 0.f, s1 = 0.f, s2 = 0.f;
    for (int n = half; n < NHEX; n += 2)                    s0 += bf2f(xbb[n * HID + c]);
    for (int n = NHEX + half; n < NHEX + NVERT; n += 2)     s1 += bf2f(xbb[n * HID + c]);
    for (int n = NHEX + NVERT + half; n < NNODE; n += 2)    s2 += bf2f(xbb[n * HID + c]);
    ps[t] = s0; __syncthreads();
    if (half == 0) fs[c] = (ps[c] + ps[128 + c]) * (1.f / 19.f);
    __syncthreads(); ps[t] = s1; __syncthreads();
    if (half == 0) fs[128 + c] = (ps[c] + ps[128 + c]) * (1.f / 54.f);
    __syncthreads(); ps[t] = s2; __syncthreads();
    if (half == 0) fs[256 + c] = (ps[c] + ps[128 + c]) * (1.f / 72.f);
    if (t < FPLY) fs[384 + t] = playerf[((size_t)b * 4 + curp[b]) * FPLY + t];
    __syncthreads();
    float a = 0.f;
    int k0 = half * 199, k1 = half ? POOLD : 199;
    for (int k = k0; k < k1; ++k) a += fs[k] * W1[(size_t)k * HID + c];
    ps[t] = a; __syncthreads();
    if (half == 0) h1s[c] = fmaxf(b1[c] + ps[c] + ps[128 + c], 0.f);
    __syncthreads();
    float o = b2[t];
    for (int j = 0; j < HID; ++j) o += h1s[j] * W2[(size_t)j * OUTD + t];
    out[(size_t)b * OUTD + t] = o;
}

/* ---------------- workspace layout ---------------- */
static constexpr size_t alignUp(size_t v) { return (v + 255) & ~(size_t)255; }
static constexpr size_t OFF_CST  = 0;
static constexpr size_t OFF_PCK  = alignUp(OFF_CST + 5 * 73 * 4);
static constexpr size_t OFF_WVB  = alignUp(OFF_PCK + 5 * 144 * 4);
static constexpr size_t OFF_WP   = alignUp(OFF_WVB + (size_t)15 * 16 * 128 * 2);
static constexpr size_t OFF_XA   = alignUp(OFF_WP + (size_t)15 * 4 * 128 * 128 * 2);
static constexpr size_t OFF_XB2  = alignUp(OFF_XA + (size_t)NB * NNODE * HID * 2);

extern "C" void kernel_launch(void* const* d_in, const int* in_sizes, int n_in,
                              void* d_out, int out_size, void* d_ws, size_t ws_size,
                              hipStream_t stream) {
    (void)in_sizes; (void)n_in; (void)out_size; (void)ws_size;
    const float* hexf   = (const float*)d_in[0];
    const float* vertf  = (const float*)d_in[1];
    const float* edgef  = (const float*)d_in[2];
    const float* playerf= (const float*)d_in[3];
    const float* inhW   = (const float*)d_in[4];
    const float* inhb   = (const float*)d_in[5];
    const float* invW   = (const float*)d_in[6];
    const float* invb   = (const float*)d_in[7];
    const float* ineW   = (const float*)d_in[8];
    const float* ineb   = (const float*)d_in[9];
    const float* gatW   = (const float*)d_in[10];
    const float* gatas  = (const float*)d_in[11];
    const float* gatad  = (const float*)d_in[12];
    const float* gatb   = (const float*)d_in[13];
    const float* lngp   = (const float*)d_in[14];
    const float* lnbp   = (const float*)d_in[15];
    const float* mW1    = (const float*)d_in[16];
    const float* mb1    = (const float*)d_in[17];
    const float* mW2    = (const float*)d_in[18];
    const float* mb2    = (const float*)d_in[19];
    const int*   curp   = (const int*)d_in[20];
    float* out = (float*)d_out;

    char* ws = (char*)d_ws;
    int* cst        = (int*)(ws + OFF_CST);
    unsigned* pck   = (unsigned*)(ws + OFF_PCK);
    ushort_t* wvb   = (ushort_t*)(ws + OFF_WVB);
    ushort_t* Wp    = (ushort_t*)(ws + OFF_WP);
    ushort_t* xbA   = (ushort_t*)(ws + OFF_XA);
    ushort_t* xbB   = (ushort_t*)(ws + OFF_XB2);

    k_pre<<<76 + NB, 256, 0, stream>>>(cst, pck, gatW, gatas, gatad, wvb, Wp,
                                       hexf, vertf, edgef, inhW, inhb, invW, invb, ineW, ineb, xbA);

    for (int l = 0; l < NLAYERS; ++l) {
        const ushort_t* cur = (l & 1) ? xbB : xbA;
        ushort_t* nxt = (l & 1) ? xbA : xbB;
        k_layer<<<3 * NB, 256, SMEM_TOT, stream>>>(cur, nxt, cst, pck, wvb, Wp, gatb, lngp, lnbp, l);
    }

    k_head<<<NB, 256, 0, stream>>>(xbB, playerf, curp, mW1, mb1, mW2, mb2, out);
}